// Round 4
// baseline (142.768 us; speedup 1.0000x reference)
//
#include <hip/hip_runtime.h>

// vol [B=2, 192,192,192, C=1] fp32, affine [B,3,4] fp32,
// out [B,192,192,192,1] fp32.
#define DIM   192
#define PLANE (DIM * DIM)
#define NB    2
#define BW    64   // w cols per block (one wave wide)
#define BH    8    // h rows per block
#define BD    32   // d depth per block (deep column tile)
#define NDT   (DIM / BD)   // 6 d-tiles

typedef float f2 __attribute__((ext_vector_type(2), aligned(4)));

// R0-R3 post-mortem ledger: runtime is PROPORTIONAL to L1-miss bytes
// (sum of per-block unique input slab) and INVARIANT to occupancy (R1),
// VMEM instruction count (R3: halved -> no change), and load batching.
// R2's 2.2x slab inflation gave exactly 2.2x runtime. Signature of an
// MSHR-bound kernel: per-CU miss slots saturate at any occupancy;
// time ~ miss-bytes * miss-latency / MSHR ~ 0.36 us/MB.
// Lever: cut halo replication. R0 tiles (64x4h x4d): slab 66x6x6 ->
// 2.3x unique volume = 131 MB. This version: deep-d column tiles
// (64w x 8h x 32d): slab 66x10x34 -> 1.29x = 73 MB. Cross-plane reuse
// becomes in-block L1 hits (per-iter footprint ~5 KB).
__global__ __launch_bounds__(BW * BH) void
SpatialTransformer_warp_kernel(const float* __restrict__ vol,
                               const float* __restrict__ affine,
                               float* __restrict__ out) {
    const int tid = threadIdx.x;
    const int w   = blockIdx.x * BW + (tid & 63);
    const int h   = blockIdx.y * BH + (tid >> 6);
    const int z   = blockIdx.z;                 // b*NDT + d-tile
    const int b   = (z >= NDT) ? 1 : 0;
    const int d0  = (z - b * NDT) * BD;

    const float* __restrict__ A = affine + b * 12;
    const float a00 = A[0], a01 = A[1], a02 = A[2],  a03 = A[3];
    const float a10 = A[4], a11 = A[5], a12 = A[6],  a13 = A[7];
    const float a20 = A[8], a21 = A[9], a22 = A[10], a23 = A[11];

    const float center = (DIM - 1) * 0.5f;   // 95.5
    const float maxl   = (float)(DIM - 1);   // 191.0
    const float maxi0  = (float)(DIM - 2);   // 190.0
    const float fplane = (float)PLANE;       // 36864.0
    const float fdim   = (float)DIM;         // 192.0

    const float ch = (float)h - center;
    const float cw = (float)w - center;

    // Partial sums independent of d
    const float pd = a01 * ch + a02 * cw + a03 + center;
    const float ph = a11 * ch + a12 * cw + a13 + center;
    const float pw = a21 * ch + a22 * cw + a23 + center;

    const float* __restrict__ vb = vol + (size_t)b * DIM * PLANE;
    float* __restrict__ ob = out + ((size_t)b * DIM + d0) * PLANE
                                 + (size_t)h * DIM + w;

    // Deep d loop: one output per iteration. Body identical to the
    // R0-proven-exact arithmetic (absmax 0.015625).
#pragma unroll 4
    for (int k = 0; k < BD; ++k) {
        const float cd = (float)(d0 + k) - center;
        const float ld = __builtin_fmaf(a00, cd, pd);
        const float lh = __builtin_fmaf(a10, cd, ph);
        const float lw = __builtin_fmaf(a20, cd, pw);

        // t = clamp(l,0,191); f = min(floor(t),190); i1 = f+1;
        // floor-corner weight = f+1-t  (reference semantics).
        const float td = __builtin_amdgcn_fmed3f(ld, 0.0f, maxl);
        const float th = __builtin_amdgcn_fmed3f(lh, 0.0f, maxl);
        const float tw = __builtin_amdgcn_fmed3f(lw, 0.0f, maxl);

        const float fd = fminf(floorf(td), maxi0);
        const float fh = fminf(floorf(th), maxi0);
        const float fw = fminf(floorf(tw), maxi0);

        const float w0d = fd + 1.0f - td;
        const float w0h = fh + 1.0f - th;
        const float w0w = fw + 1.0f - tw;

        // Flat index in float: integer-valued, < 2^24 -> exact.
        const int idx = (int)__builtin_fmaf(fd, fplane, __builtin_fmaf(fh, fdim, fw));
        const float* p = vb + idx;

        const f2 r00 = *(const f2*)(p);                 // (fd,   fh,   fw..fw+1)
        const f2 r01 = *(const f2*)(p + DIM);           // (fd,   fh+1)
        const f2 r10 = *(const f2*)(p + PLANE);         // (fd+1, fh)
        const f2 r11 = *(const f2*)(p + PLANE + DIM);   // (fd+1, fh+1)

        const float w1w = 1.0f - w0w;
        const float w1h = 1.0f - w0h;
        const float w1d = 1.0f - w0d;

        const float x00 = r00.x * w0w + r00.y * w1w;
        const float x01 = r01.x * w0w + r01.y * w1w;
        const float x10 = r10.x * w0w + r10.y * w1w;
        const float x11 = r11.x * w0w + r11.y * w1w;

        const float y0 = x00 * w0h + x01 * w1h;
        const float y1 = x10 * w0h + x11 * w1h;

        __builtin_nontemporal_store(y0 * w0d + y1 * w1d, ob + k * PLANE);
    }
}

extern "C" void kernel_launch(void* const* d_in, const int* in_sizes, int n_in,
                              void* d_out, int out_size, void* d_ws, size_t ws_size,
                              hipStream_t stream) {
    const float* vol    = (const float*)d_in[0];
    const float* affine = (const float*)d_in[1];
    float* out = (float*)d_out;

    dim3 grid(DIM / BW, DIM / BH, NB * NDT);   // (3, 24, 12) = 864 blocks
    dim3 block(BW * BH);                       // 512
    SpatialTransformer_warp_kernel<<<grid, block, 0, stream>>>(vol, affine, out);
}

// Round 5
// 130.933 us; speedup vs baseline: 1.0904x; 1.0904x over previous
//
#include <hip/hip_runtime.h>

// vol [B=2, 192,192,192, C=1] fp32, affine [B,3,4] fp32,
// out [B,192,192,192,1] fp32.
#define DIM   192
#define PLANE (DIM * DIM)
#define NB    2
#define DPT   4   // d-voxels per thread
#define BH    4   // h rows per block

typedef float f2 __attribute__((ext_vector_type(2), aligned(4)));

// Ledger R0-R4: runtime invariant to occupancy (R1), VMEM instr count (R3),
// HBM fetch bytes (R3/R4). Consistent wall: L1/TA line-request throughput
// (~3 line-req/cy/CU incl. L1 hits). R0 spends 16 gather-loads/thread; but
// in d, output k's floor plane == output k-1's ceil plane for ~94% of lanes
// (a00~1): r00/r01[k] forwardable from r10/r11[k-1]. This version loads only
// the 2 new-plane rows for k>=1 (10 unconditional loads vs 16) + exec-masked
// patch loads for non-forwardable lanes; select by cndmask at consume.
// Forwarded data is from identical addresses -> bit-identical results.
__global__ __launch_bounds__(256) __attribute__((amdgpu_waves_per_eu(4, 4))) void
SpatialTransformer_warp_kernel(const float* __restrict__ vol,
                               const float* __restrict__ affine,
                               float* __restrict__ out) {
    const int tid = threadIdx.x;
    const int w   = (blockIdx.x << 6) + (tid & 63);   // 64-lane wave along w
    const int h   = blockIdx.y * BH + (tid >> 6);     // 4 h rows per block
    const int z   = blockIdx.z;                       // (d-quad | b)
    const int b   = (z >= DIM / DPT) ? 1 : 0;
    const int d0  = (z - b * (DIM / DPT)) * DPT;

    const float* __restrict__ A = affine + b * 12;
    const float a00 = A[0], a01 = A[1], a02 = A[2],  a03 = A[3];
    const float a10 = A[4], a11 = A[5], a12 = A[6],  a13 = A[7];
    const float a20 = A[8], a21 = A[9], a22 = A[10], a23 = A[11];

    const float center = (DIM - 1) * 0.5f;   // 95.5
    const float maxl   = (float)(DIM - 1);   // 191.0
    const float maxi0  = (float)(DIM - 2);   // 190.0
    const float fplane = (float)PLANE;       // 36864.0
    const float fdim   = (float)DIM;         // 192.0

    const float ch = (float)h - center;
    const float cw = (float)w - center;

    const float pd = a01 * ch + a02 * cw + a03 + center;
    const float ph = a11 * ch + a12 * cw + a13 + center;
    const float pw = a21 * ch + a22 * cw + a23 + center;

    const float* __restrict__ vb = vol + (size_t)b * DIM * PLANE;
    float* __restrict__ ob = out + ((size_t)b * DIM + d0) * PLANE
                                 + (size_t)h * DIM + w;

    // ---- pure-arithmetic phase: indices, weights, forwarding masks ----
    float fd_[DPT], fh_[DPT], fw_[DPT];
    float w0d_[DPT], w0h_[DPT], w0w_[DPT];
    int   idx_[DPT];
#pragma unroll
    for (int k = 0; k < DPT; ++k) {
        const float cd = (float)(d0 + k) - center;
        const float td = __builtin_amdgcn_fmed3f(__builtin_fmaf(a00, cd, pd), 0.0f, maxl);
        const float th = __builtin_amdgcn_fmed3f(__builtin_fmaf(a10, cd, ph), 0.0f, maxl);
        const float tw = __builtin_amdgcn_fmed3f(__builtin_fmaf(a20, cd, pw), 0.0f, maxl);

        const float fd = fminf(floorf(td), maxi0);
        const float fh = fminf(floorf(th), maxi0);
        const float fw = fminf(floorf(tw), maxi0);

        fd_[k] = fd; fh_[k] = fh; fw_[k] = fw;
        w0d_[k] = fd + 1.0f - td;
        w0h_[k] = fh + 1.0f - th;
        w0w_[k] = fw + 1.0f - tw;
        // Flat index in float: integer-valued, < 2^24 -> exact.
        idx_[k] = (int)__builtin_fmaf(fd, fplane, __builtin_fmaf(fh, fdim, fw));
    }

    bool fwd_[DPT];
    fwd_[0] = false;
#pragma unroll
    for (int k = 1; k < DPT; ++k)
        fwd_[k] = (fd_[k] == fd_[k - 1] + 1.0f) &
                  (fh_[k] == fh_[k - 1]) &
                  (fw_[k] == fw_[k - 1]);

    // ---- load phase: 10 unconditional + up to 6 exec-masked patches ----
    f2 r00_0, r01_0;                 // k=0 floor plane
    f2 r10_[DPT], r11_[DPT];         // ceil plane, all k
    f2 p00_[DPT], p01_[DPT];         // patches for non-forwarded lanes (k>=1)

    {
        const float* p = vb + idx_[0];
        r00_0    = *(const f2*)(p);
        r01_0    = *(const f2*)(p + DIM);
        r10_[0]  = *(const f2*)(p + PLANE);
        r11_[0]  = *(const f2*)(p + PLANE + DIM);
    }
#pragma unroll
    for (int k = 1; k < DPT; ++k) {
        const float* p = vb + idx_[k];
        r10_[k] = *(const f2*)(p + PLANE);
        r11_[k] = *(const f2*)(p + PLANE + DIM);
        p00_[k] = (f2){0.0f, 0.0f};
        p01_[k] = (f2){0.0f, 0.0f};
        if (!fwd_[k]) {              // exec-masked gather, ~6% of lanes
            p00_[k] = *(const f2*)(p);
            p01_[k] = *(const f2*)(p + DIM);
        }
    }

    // Scheduling fence: whole batch issued, one vmcnt drain.
    __builtin_amdgcn_sched_barrier(0);

    // ---- consume ----
#pragma unroll
    for (int k = 0; k < DPT; ++k) {
        const f2 r00 = (k == 0) ? r00_0 : (fwd_[k] ? r10_[k - 1] : p00_[k]);
        const f2 r01 = (k == 0) ? r01_0 : (fwd_[k] ? r11_[k - 1] : p01_[k]);
        const f2 r10 = r10_[k];
        const f2 r11 = r11_[k];

        const float w0w = w0w_[k], w1w = 1.0f - w0w;
        const float w0h = w0h_[k], w1h = 1.0f - w0h;
        const float w0d = w0d_[k], w1d = 1.0f - w0d;

        const float x00 = r00.x * w0w + r00.y * w1w;
        const float x01 = r01.x * w0w + r01.y * w1w;
        const float x10 = r10.x * w0w + r10.y * w1w;
        const float x11 = r11.x * w0w + r11.y * w1w;

        const float y0 = x00 * w0h + x01 * w1h;
        const float y1 = x10 * w0h + x11 * w1h;

        __builtin_nontemporal_store(y0 * w0d + y1 * w1d, ob + k * PLANE);
    }
}

extern "C" void kernel_launch(void* const* d_in, const int* in_sizes, int n_in,
                              void* d_out, int out_size, void* d_ws, size_t ws_size,
                              hipStream_t stream) {
    const float* vol    = (const float*)d_in[0];
    const float* affine = (const float*)d_in[1];
    float* out = (float*)d_out;

    dim3 grid(DIM / 64, DIM / BH, NB * (DIM / DPT));  // (3, 48, 96)
    dim3 block(256);
    SpatialTransformer_warp_kernel<<<grid, block, 0, stream>>>(vol, affine, out);
}

// Round 6
// 124.727 us; speedup vs baseline: 1.1446x; 1.0498x over previous
//
#include <hip/hip_runtime.h>

// vol [B=2, 192,192,192, C=1] fp32, affine [B,3,4] fp32,
// out [B,192,192,192,1] fp32.
#define DIM   192
#define PLANE (DIM * DIM)
#define NB    2
#define WPT   4   // consecutive w per thread -> one dwordx4 store
#define BH    16  // h rows per block (4 waves x 4 h-groups)
#define BW    64  // w span per block

typedef float f2 __attribute__((ext_vector_type(2), aligned(4)));
typedef float f4v __attribute__((ext_vector_type(4), aligned(16)));

// Ledger R0-R5: runtime == 26cy x (VMEM wave-instructions), invariant to
// occupancy (R1), fetch bytes (R3/R4), lines/instr (R3), and exec-masked
// "savings" (R3/R5: per-lane patches issue ~every wave since
// 1-(1-p)^64 ~= 1 at p~5%). No round ever REDUCED the count. This one does,
// with zero patch/extraction logic: thread = 4 consecutive w at one (d,h);
// the 16 corner gathers are unchanged per-output dwordx2 (own fd/fh/fw),
// but 4 dword stores fuse into 1 dwordx4. 20 -> 17 wave-instr (-15%).
__global__ __launch_bounds__(256) __attribute__((amdgpu_waves_per_eu(4, 4))) void
SpatialTransformer_warp_kernel(const float* __restrict__ vol,
                               const float* __restrict__ affine,
                               float* __restrict__ out) {
    const int tid = threadIdx.x;
    const int l   = tid & 63;                          // lane
    const int wv  = tid >> 6;                          // wave in block
    const int w0  = blockIdx.x * BW + ((l & 15) << 2); // 16 lanes x 4w = 64w
    const int h   = blockIdx.y * BH + (wv << 2) + (l >> 4); // 4 h-groups/wave
    const int z   = blockIdx.z;                        // d | b
    const int b   = (z >= DIM) ? 1 : 0;
    const int d   = z - b * DIM;

    const float* __restrict__ A = affine + b * 12;
    const float a00 = A[0], a01 = A[1], a02 = A[2],  a03 = A[3];
    const float a10 = A[4], a11 = A[5], a12 = A[6],  a13 = A[7];
    const float a20 = A[8], a21 = A[9], a22 = A[10], a23 = A[11];

    const float center = (DIM - 1) * 0.5f;   // 95.5
    const float maxl   = (float)(DIM - 1);   // 191.0
    const float maxi0  = (float)(DIM - 2);   // 190.0
    const float fplane = (float)PLANE;       // 36864.0
    const float fdim   = (float)DIM;         // 192.0

    const float cd = (float)d - center;
    const float ch = (float)h - center;
    const float cw = (float)w0 - center;

    // Partial sums independent of w (w advances by +1.0f per output)
    const float pd = __builtin_fmaf(a00, cd, __builtin_fmaf(a01, ch, a03 + center));
    const float ph = __builtin_fmaf(a10, cd, __builtin_fmaf(a11, ch, a13 + center));
    const float pw = __builtin_fmaf(a20, cd, __builtin_fmaf(a21, ch, a23 + center));

    const float* __restrict__ vb = vol + (size_t)b * DIM * PLANE;
    float* __restrict__ ob = out + ((size_t)b * DIM + d) * PLANE
                                 + (size_t)h * DIM + w0;

    f2 r00[WPT], r01[WPT], r10[WPT], r11[WPT];
    float w0d_[WPT], w0h_[WPT], w0w_[WPT];

    // ---- batch: addresses + all 16 gathers (identical per-output semantics
    // to R0: t = clamp(l,0,191); f = min(floor(t),190); weight = f+1-t) ----
#pragma unroll
    for (int i = 0; i < WPT; ++i) {
        const float cwi = cw + (float)i;
        const float td = __builtin_amdgcn_fmed3f(__builtin_fmaf(a02, cwi, pd), 0.0f, maxl);
        const float th = __builtin_amdgcn_fmed3f(__builtin_fmaf(a12, cwi, ph), 0.0f, maxl);
        const float tw = __builtin_amdgcn_fmed3f(__builtin_fmaf(a22, cwi, pw), 0.0f, maxl);

        const float fd = fminf(floorf(td), maxi0);
        const float fh = fminf(floorf(th), maxi0);
        const float fw = fminf(floorf(tw), maxi0);

        w0d_[i] = fd + 1.0f - td;
        w0h_[i] = fh + 1.0f - th;
        w0w_[i] = fw + 1.0f - tw;

        // Flat index in float: integer-valued, < 2^24 -> exact.
        const int idx = (int)__builtin_fmaf(fd, fplane, __builtin_fmaf(fh, fdim, fw));
        const float* p = vb + idx;

        r00[i] = *(const f2*)(p);                   // (fd,   fh,   fw..fw+1)
        r01[i] = *(const f2*)(p + DIM);             // (fd,   fh+1)
        r10[i] = *(const f2*)(p + PLANE);           // (fd+1, fh)
        r11[i] = *(const f2*)(p + PLANE + DIM);     // (fd+1, fh+1)
    }

    // Whole 16-load batch in flight, one drain.
    __builtin_amdgcn_sched_barrier(0);

    // ---- consume ----
    f4v res;
#pragma unroll
    for (int i = 0; i < WPT; ++i) {
        const float w0w = w0w_[i], w1w = 1.0f - w0w;
        const float w0h = w0h_[i], w1h = 1.0f - w0h;
        const float w0d = w0d_[i], w1d = 1.0f - w0d;

        const float x00 = r00[i].x * w0w + r00[i].y * w1w;
        const float x01 = r01[i].x * w0w + r01[i].y * w1w;
        const float x10 = r10[i].x * w0w + r10[i].y * w1w;
        const float x11 = r11[i].x * w0w + r11[i].y * w1w;

        const float y0 = x00 * w0h + x01 * w1h;
        const float y1 = x10 * w0h + x11 * w1h;

        res[i] = y0 * w0d + y1 * w1d;
    }

    // Fused store: 4 outputs -> one dwordx4 (16B-aligned, w0 % 4 == 0).
    __builtin_nontemporal_store(res, (f4v*)ob);
}

extern "C" void kernel_launch(void* const* d_in, const int* in_sizes, int n_in,
                              void* d_out, int out_size, void* d_ws, size_t ws_size,
                              hipStream_t stream) {
    const float* vol    = (const float*)d_in[0];
    const float* affine = (const float*)d_in[1];
    float* out = (float*)d_out;

    dim3 grid(DIM / BW, DIM / BH, NB * DIM);   // (3, 12, 384)
    dim3 block(256);
    SpatialTransformer_warp_kernel<<<grid, block, 0, stream>>>(vol, affine, out);
}